// Round 5
// baseline (197.604 us; speedup 1.0000x reference)
//
#include <hip/hip_runtime.h>
#include <hip/hip_fp16.h>
#include <math.h>

#define DIM 128
#define NVOX (DIM*DIM*DIM)

// R9 LDS tiling: 8^3 voxel tile per block, staged 16^3 halo (PAD=4 each side).
#define TILE 8
#define PAD 4
#define SREG 16                      // TILE + 2*PAD
#define NSLOT (SREG*SREG*SREG)       // 4096 staged voxels
// 12 B/voxel in LDS (3 dwords): 48 KB -> 3 blocks/CU by LDS; stride-3 dwords
// spreads random gather addresses over all 32 banks (gcd(3,32)=1).

typedef float vfloat4 __attribute__((ext_vector_type(4)));
typedef unsigned int vuint4 __attribute__((ext_vector_type(4)));
typedef unsigned int vuint3 __attribute__((ext_vector_type(3)));  // sizeof==16
static_assert(sizeof(vuint3) == 16, "vuint3 stride assumption");

// ---------------- Pass A: dti (6,NVOX) f32 SoA -> AoS fp16, 16B-stride -------
// (12 B payload per voxel; .w never read so store only 3 dwords.)
__global__ __launch_bounds__(256) void pack_dti_kernel(
    const float* __restrict__ dti, unsigned int* __restrict__ aos)
{
    const int bid = blockIdx.x;                    // 2048 blocks
    const int sb = ((bid & 7) << 8) | (bid >> 3);  // XCD i-slab swizzle
    const int id4 = (sb * 256 + (int)threadIdx.x) * 4;

    const vfloat4 v0 = __builtin_nontemporal_load(reinterpret_cast<const vfloat4*>(dti + 0 * NVOX + id4));
    const vfloat4 v1 = __builtin_nontemporal_load(reinterpret_cast<const vfloat4*>(dti + 1 * NVOX + id4));
    const vfloat4 v2 = __builtin_nontemporal_load(reinterpret_cast<const vfloat4*>(dti + 2 * NVOX + id4));
    const vfloat4 v3 = __builtin_nontemporal_load(reinterpret_cast<const vfloat4*>(dti + 3 * NVOX + id4));
    const vfloat4 v4 = __builtin_nontemporal_load(reinterpret_cast<const vfloat4*>(dti + 4 * NVOX + id4));
    const vfloat4 v5 = __builtin_nontemporal_load(reinterpret_cast<const vfloat4*>(dti + 5 * NVOX + id4));

    auto packone = [&](float a0, float a1, float a2, float a3, float a4,
                       float a5, int idx) {
        const __half2 h01 = __floats2half2_rn(a0, a1);
        const __half2 h23 = __floats2half2_rn(a2, a3);
        const __half2 h45 = __floats2half2_rn(a4, a5);
        vuint3 q;
        q.x = *reinterpret_cast<const unsigned int*>(&h01);
        q.y = *reinterpret_cast<const unsigned int*>(&h23);
        q.z = *reinterpret_cast<const unsigned int*>(&h45);
        *reinterpret_cast<vuint3*>(aos + 4 * idx) = q;  // 12B store, 16B stride
    };
    packone(v0.x, v1.x, v2.x, v3.x, v4.x, v5.x, id4 + 0);
    packone(v0.y, v1.y, v2.y, v3.y, v4.y, v5.y, id4 + 1);
    packone(v0.z, v1.z, v2.z, v3.z, v4.z, v5.z, id4 + 2);
    packone(v0.w, v1.w, v2.w, v3.w, v4.w, v5.w, id4 + 3);
}

// ---- fp32 polar factor: branch-free 3 scaled + 2 unscaled Newton ------------
__device__ __forceinline__ bool polar_f32(const float J[9], float X[9])
{
#pragma unroll
    for (int t = 0; t < 9; ++t) X[t] = J[t];
    bool bad = false;
#pragma unroll
    for (int it = 0; it < 5; ++it) {
        float C[9];
        C[0] = X[4] * X[8] - X[5] * X[7];
        C[1] = X[5] * X[6] - X[3] * X[8];
        C[2] = X[3] * X[7] - X[4] * X[6];
        C[3] = X[2] * X[7] - X[1] * X[8];
        C[4] = X[0] * X[8] - X[2] * X[6];
        C[5] = X[1] * X[6] - X[0] * X[7];
        C[6] = X[1] * X[5] - X[2] * X[4];
        C[7] = X[2] * X[3] - X[0] * X[5];
        C[8] = X[0] * X[4] - X[1] * X[3];
        const float det = X[0] * C[0] + X[1] * C[1] + X[2] * C[2];
        float a, b;
        if (it < 3) {
            float nX = 0.0f, nC = 0.0f;
#pragma unroll
            for (int t = 0; t < 9; ++t) { nX += X[t] * X[t]; nC += C[t] * C[t]; }
            if (it == 0)
                bad = !(nX * nC < 4.0e6f * det * det);  // condF > 2e3 (sqrt-free)
            const float s = __builtin_amdgcn_sqrtf(nC * __builtin_amdgcn_rcpf(nX));
            const float r = __builtin_amdgcn_rsqf(s * fabsf(det));
            a = 0.5f * s * r;
            b = copysignf(0.5f * r, det);
        } else {
            a = 0.5f;
            b = 0.5f * __builtin_amdgcn_rcpf(det);
        }
#pragma unroll
        for (int t = 0; t < 9; ++t) X[t] = a * X[t] + b * C[t];
    }
    return bad;
}

// ---- fp64 fallback (rare; inline & unrolled => register-resident) -----------
__device__ __forceinline__ void polar_f64(const float J[9], float X[9])
{
    double Y[9];
#pragma unroll
    for (int t = 0; t < 9; ++t) Y[t] = (double)J[t];
    for (int it = 0; it < 20; ++it) {
        double C[9];
        C[0] = Y[4] * Y[8] - Y[5] * Y[7];
        C[1] = Y[5] * Y[6] - Y[3] * Y[8];
        C[2] = Y[3] * Y[7] - Y[4] * Y[6];
        C[3] = Y[2] * Y[7] - Y[1] * Y[8];
        C[4] = Y[0] * Y[8] - Y[2] * Y[6];
        C[5] = Y[1] * Y[6] - Y[0] * Y[7];
        C[6] = Y[1] * Y[5] - Y[2] * Y[4];
        C[7] = Y[2] * Y[3] - Y[0] * Y[5];
        C[8] = Y[0] * Y[4] - Y[1] * Y[3];
        const double det = Y[0] * C[0] + Y[1] * C[1] + Y[2] * C[2];
        if (!(fabs(det) > 1e-300)) break;
        double nX = 0.0, nC = 0.0;
#pragma unroll
        for (int t = 0; t < 9; ++t) { nX += Y[t] * Y[t]; nC += C[t] * C[t]; }
        const double g = sqrt(sqrt(nC) / (fabs(det) * sqrt(nX)));
        const double a = 0.5 * g;
        const double b = 0.5 / (g * det);
        double diff2 = 0.0, n2 = 0.0;
#pragma unroll
        for (int t = 0; t < 9; ++t) {
            const double y = a * Y[t] + b * C[t];
            const double d = y - Y[t];
            diff2 += d * d; n2 += y * y;
            Y[t] = y;
        }
        if (diff2 <= 1e-26 * n2) break;
    }
#pragma unroll
    for (int t = 0; t < 9; ++t) X[t] = (float)Y[t];
}

// ---------------- Pass B: stage halo -> LDS gather + polar + congruence ------
// R9: the 8 random 16B gathers/voxel were ~16M L2 requests/dispatch ≈ 80% of
// the chip's L2 request rate (8 XCD x 16 ch x 1/cy) — the real bottleneck
// (ILP/scheduling changes R6-R8 were all neutral: throughput-, not
// latency-bound). Displacement ~N(0,1) => samples are quasi-local. Stage the
// 16^3 halo (PAD=4 covers |u|<4; miss prob ~6e-5/comp) into LDS with
// coalesced line loads (~2 line-requests/voxel instead of ~5-8), gather the
// 8 corners from LDS (idle pipe). Out-of-halo voxels take the exact global
// path (same 12B payloads => bit-identical results).
__global__ __launch_bounds__(512) void warp_dti_kernel(
    const unsigned int* __restrict__ aos,   // 16B-stride AoS, 12B payload
    const float* __restrict__ ddf,
    float* __restrict__ out)
{
    __shared__ unsigned int sm[NSLOT * 3];  // 48 KB

    const int bid = blockIdx.x;                     // 4096 blocks
    const int sb = ((bid & 7) << 9) | (bid >> 3);   // XCD i-slab swizzle
    const int tx = sb >> 8, ty = (sb >> 4) & 15, tz = sb & 15;
    const int bx = tx << 3, by = ty << 3, bz = tz << 3;
    const int t = (int)threadIdx.x;

    // ---- stage 16^3 halo: 8 slots/thread, z-contiguous => coalesced ----
#pragma unroll
    for (int r = 0; r < 8; ++r) {
        const int s = t + (r << 9);
        const int lx = s >> 8, ly = (s >> 4) & 15, lz = s & 15;
        const int gx = min(max(bx - PAD + lx, 0), DIM - 1);
        const int gy = min(max(by - PAD + ly, 0), DIM - 1);
        const int gz = min(max(bz - PAD + lz, 0), DIM - 1);
        const unsigned int* gp = aos + (((gx << 14) | (gy << 7) | gz) << 2);
        const vuint3 q = *reinterpret_cast<const vuint3*>(gp);  // 12B load
        const int o = s * 3;
        sm[o + 0] = q.x; sm[o + 1] = q.y; sm[o + 2] = q.z;
    }
    __syncthreads();

    // ---- this thread's voxel ----
    const int vx = t >> 6, vy = (t >> 3) & 7, vz = t & 7;
    const int i = bx + vx, j = by + vy, k = bz + vz;
    const int id = (i << 14) | (j << 7) | k;

    // ---- displacement + Jacobian neighbor loads (coalesced global) ----
    const float* __restrict__ p0_ = ddf;
    const float* __restrict__ p1_ = ddf + NVOX;
    const float* __restrict__ p2_ = ddf + 2 * NVOX;

    const int im = (i > 0) ? i - 1 : 0, ip = (i < DIM - 1) ? i + 1 : DIM - 1;
    const int jm = (j > 0) ? j - 1 : 0, jp = (j < DIM - 1) ? j + 1 : DIM - 1;
    const int km = (k > 0) ? k - 1 : 0, kp = (k < DIM - 1) ? k + 1 : DIM - 1;
    const float si = (ip - im == 2) ? 0.5f : 1.0f;
    const float sj = (jp - jm == 2) ? 0.5f : 1.0f;
    const float sk = (kp - km == 2) ? 0.5f : 1.0f;

    const int l_ip = (ip << 14) | (j << 7) | k;
    const int l_im = (im << 14) | (j << 7) | k;
    const int l_jp = (i << 14) | (jp << 7) | k;
    const int l_jm = (i << 14) | (jm << 7) | k;
    const int l_kp = (i << 14) | (j << 7) | kp;
    const int l_km = (i << 14) | (j << 7) | km;

    float J[9];
    float u[3];
#pragma unroll
    for (int c = 0; c < 3; ++c) {
        const float* __restrict__ p = (c == 0) ? p0_ : (c == 1) ? p1_ : p2_;
        u[c] = p[id];
        J[c * 3 + 0] = (p[l_ip] - p[l_im]) * si;
        J[c * 3 + 1] = (p[l_jp] - p[l_jm]) * sj;
        J[c * 3 + 2] = (p[l_kp] - p[l_km]) * sk;
        J[c * 3 + c] += 1.0f;
    }

    // ---- trilinear corner setup (border padding) ----
    const float cx = fminf(fmaxf((float)i + u[0], 0.0f), (float)(DIM - 1));
    const float cy = fminf(fmaxf((float)j + u[1], 0.0f), (float)(DIM - 1));
    const float cz = fminf(fmaxf((float)k + u[2], 0.0f), (float)(DIM - 1));
    const float x0f = floorf(cx), y0f = floorf(cy), z0f = floorf(cz);
    const float fx = cx - x0f, fy = cy - y0f, fz = cz - z0f;
    const int x0 = (int)x0f, y0 = (int)y0f, z0 = (int)z0f;
    const int x1 = min(x0 + 1, DIM - 1);
    const int y1 = min(y0 + 1, DIM - 1);
    const int z1 = min(z0 + 1, DIM - 1);

    // local (staged) coords; in-halo iff all six in [0,15]
    const int lx0 = x0 - bx + PAD, ly0 = y0 - by + PAD, lz0 = z0 - bz + PAD;
    const int lx1 = x1 - bx + PAD, ly1 = y1 - by + PAD, lz1 = z1 - bz + PAD;
    const bool intile =
        ((unsigned)(lx0 | ly0 | lz0 | lx1 | ly1 | lz1) < (unsigned)SREG);

    unsigned int w0[3], w1[3], w2[3], w3[3], w4[3], w5[3], w6[3], w7[3];
    if (__builtin_expect(intile, 1)) {
        const int l000 = (lx0 << 8) | (ly0 << 4) | lz0;
        const int ldz = lz1 - lz0;
        const int ldy = (ly1 - ly0) << 4;
        const int ldx = (lx1 - lx0) << 8;
        auto lds3 = [&](int lin, unsigned int* d) {
            const int o = lin * 3;
            d[0] = sm[o]; d[1] = sm[o + 1]; d[2] = sm[o + 2];
        };
        lds3(l000,                   w0);
        lds3(l000 + ldz,             w1);
        lds3(l000 + ldy,             w2);
        lds3(l000 + ldy + ldz,       w3);
        lds3(l000 + ldx,             w4);
        lds3(l000 + ldx + ldz,       w5);
        lds3(l000 + ldx + ldy,       w6);
        lds3(l000 + ldx + ldy + ldz, w7);
    } else {
        // rare (|u|>=4): exact global path, same payload bytes
        const int dz = z1 - z0;
        const int dy = (y1 - y0) << 7;
        const int dx = (x1 - x0) << 14;
        const int b000 = (x0 << 14) | (y0 << 7) | z0;
        auto glb3 = [&](int lin, unsigned int* d) {
            const unsigned int* gp = aos + (lin << 2);
            const vuint3 q = *reinterpret_cast<const vuint3*>(gp);
            d[0] = q.x; d[1] = q.y; d[2] = q.z;
        };
        glb3(b000,                w0);
        glb3(b000 + dz,           w1);
        glb3(b000 + dy,           w2);
        glb3(b000 + dy + dz,      w3);
        glb3(b000 + dx,           w4);
        glb3(b000 + dx + dz,      w5);
        glb3(b000 + dx + dy,      w6);
        glb3(b000 + dx + dy + dz, w7);
    }

    // ---- interp accumulate (v_fma_mix_f32 from fp16 halves) ----
    const float gx0 = 1.0f - fx, gy0 = 1.0f - fy, gz0 = 1.0f - fz;
    float acc0 = 0.0f, acc1 = 0.0f, acc2 = 0.0f;
    float acc3 = 0.0f, acc4 = 0.0f, acc5 = 0.0f;
    auto gat = [&](const unsigned int* d, float wt) {
        const __half2 h01 = *reinterpret_cast<const __half2*>(&d[0]);
        const __half2 h23 = *reinterpret_cast<const __half2*>(&d[1]);
        const __half2 h45 = *reinterpret_cast<const __half2*>(&d[2]);
        acc0 = fmaf(__half2float(__low2half(h01)), wt, acc0);
        acc1 = fmaf(__half2float(__high2half(h01)), wt, acc1);
        acc2 = fmaf(__half2float(__low2half(h23)), wt, acc2);
        acc3 = fmaf(__half2float(__high2half(h23)), wt, acc3);
        acc4 = fmaf(__half2float(__low2half(h45)), wt, acc4);
        acc5 = fmaf(__half2float(__high2half(h45)), wt, acc5);
    };
    gat(w0, gx0 * gy0 * gz0);
    gat(w1, gx0 * gy0 * fz);
    gat(w2, gx0 * fy * gz0);
    gat(w3, gx0 * fy * fz);
    gat(w4, fx * gy0 * gz0);
    gat(w5, fx * gy0 * fz);
    gat(w6, fx * fy * gz0);
    gat(w7, fx * fy * fz);

    // ---- polar factor ----
    float X[9];
    const bool bad = polar_f32(J, X);
    if (__builtin_expect(bad, 0)) polar_f64(J, X);

    // ---- Dp = R^T M R ----
    const float M00 = acc0, M01 = acc1, M11 = acc2;
    const float M02 = acc3, M12 = acc4, M22 = acc5;
    float P[9];  // P = M * R
    P[0] = M00 * X[0] + M01 * X[3] + M02 * X[6];
    P[1] = M00 * X[1] + M01 * X[4] + M02 * X[7];
    P[2] = M00 * X[2] + M01 * X[5] + M02 * X[8];
    P[3] = M01 * X[0] + M11 * X[3] + M12 * X[6];
    P[4] = M01 * X[1] + M11 * X[4] + M12 * X[7];
    P[5] = M01 * X[2] + M11 * X[5] + M12 * X[8];
    P[6] = M02 * X[0] + M12 * X[3] + M22 * X[6];
    P[7] = M02 * X[1] + M12 * X[4] + M22 * X[7];
    P[8] = M02 * X[2] + M12 * X[5] + M22 * X[8];

    // Output: 48 MB, zero reuse -> non-temporal.
    __builtin_nontemporal_store(X[0] * P[0] + X[3] * P[3] + X[6] * P[6], &out[0 * NVOX + id]);
    __builtin_nontemporal_store(X[1] * P[0] + X[4] * P[3] + X[7] * P[6], &out[1 * NVOX + id]);
    __builtin_nontemporal_store(X[1] * P[1] + X[4] * P[4] + X[7] * P[7], &out[2 * NVOX + id]);
    __builtin_nontemporal_store(X[2] * P[0] + X[5] * P[3] + X[8] * P[6], &out[3 * NVOX + id]);
    __builtin_nontemporal_store(X[2] * P[1] + X[5] * P[4] + X[8] * P[7], &out[4 * NVOX + id]);
    __builtin_nontemporal_store(X[2] * P[2] + X[5] * P[5] + X[8] * P[8], &out[5 * NVOX + id]);
}

extern "C" void kernel_launch(void* const* d_in, const int* in_sizes, int n_in,
                              void* d_out, int out_size, void* d_ws, size_t ws_size,
                              hipStream_t stream) {
    const float* dti = (const float*)d_in[0];
    const float* ddf = (const float*)d_in[1];
    float* out = (float*)d_out;
    unsigned int* aos = (unsigned int*)d_ws;  // 2M voxels * 16 B = 32 MB scratch

    hipLaunchKernelGGL(pack_dti_kernel, dim3(NVOX / 1024), dim3(256), 0, stream,
                       dti, aos);
    hipLaunchKernelGGL(warp_dti_kernel, dim3(NVOX / 512), dim3(512), 0, stream,
                       aos, ddf, out);
}

// Round 7
// 171.570 us; speedup vs baseline: 1.1517x; 1.1517x over previous
//
#include <hip/hip_runtime.h>
#include <hip/hip_fp16.h>
#include <math.h>

#define DIM 128
#define NVOX (DIM*DIM*DIM)

// clang native vector types (HIP's float4/uint4 are classes — rejected by
// __builtin_nontemporal_load/store)
typedef float vfloat4 __attribute__((ext_vector_type(4)));
typedef unsigned int vuint4 __attribute__((ext_vector_type(4)));
typedef unsigned int vuint3 __attribute__((ext_vector_type(3)));  // sizeof==16
static_assert(sizeof(vuint3) == 16, "vuint3 must stride 16B over the AoS array");

// ---------------- Pass A: dti (6,NVOX) f32 SoA -> AoS fp16, 16B-stride -------
// 12 B payload per voxel (the 4th dword is never read) — saves 8 MB of HBM
// writes vs 16 B stores. nt loads: dti is dead after this pass; keep it out
// of L2/L3 so the aos array stays resident for pass B's gathers.
__global__ __launch_bounds__(256) void pack_dti_kernel(
    const float* __restrict__ dti, unsigned int* __restrict__ aos)
{
    const int bid = blockIdx.x;                    // 2048 blocks
    const int sb = ((bid & 7) << 8) | (bid >> 3);  // XCD i-slab swizzle
    const int id4 = (sb * 256 + (int)threadIdx.x) * 4;

    const vfloat4 v0 = __builtin_nontemporal_load(reinterpret_cast<const vfloat4*>(dti + 0 * NVOX + id4));
    const vfloat4 v1 = __builtin_nontemporal_load(reinterpret_cast<const vfloat4*>(dti + 1 * NVOX + id4));
    const vfloat4 v2 = __builtin_nontemporal_load(reinterpret_cast<const vfloat4*>(dti + 2 * NVOX + id4));
    const vfloat4 v3 = __builtin_nontemporal_load(reinterpret_cast<const vfloat4*>(dti + 3 * NVOX + id4));
    const vfloat4 v4 = __builtin_nontemporal_load(reinterpret_cast<const vfloat4*>(dti + 4 * NVOX + id4));
    const vfloat4 v5 = __builtin_nontemporal_load(reinterpret_cast<const vfloat4*>(dti + 5 * NVOX + id4));

    auto packone = [&](float a0, float a1, float a2, float a3, float a4,
                       float a5, int idx) {
        const __half2 h01 = __floats2half2_rn(a0, a1);
        const __half2 h23 = __floats2half2_rn(a2, a3);
        const __half2 h45 = __floats2half2_rn(a4, a5);
        vuint3 q;
        q.x = *reinterpret_cast<const unsigned int*>(&h01);
        q.y = *reinterpret_cast<const unsigned int*>(&h23);
        q.z = *reinterpret_cast<const unsigned int*>(&h45);
        *reinterpret_cast<vuint3*>(aos + 4 * idx) = q;  // 12B store, 16B stride
    };
    packone(v0.x, v1.x, v2.x, v3.x, v4.x, v5.x, id4 + 0);
    packone(v0.y, v1.y, v2.y, v3.y, v4.y, v5.y, id4 + 1);
    packone(v0.z, v1.z, v2.z, v3.z, v4.z, v5.z, id4 + 2);
    packone(v0.w, v1.w, v2.w, v3.w, v4.w, v5.w, id4 + 3);
}

// ---- fp32 polar factor: branch-free 3 scaled + 2 unscaled Newton ------------
// Fixed point: R = U @ Vh (SVD polar factor), sign(det) preserved.
// For cond<=2e3: scaled iters contract sigma-range 22 -> 2.5 -> 1.1, then
// unscaled e^2/2: 0.1 -> 5e-3 -> 1.3e-5 (orthogonality; output perturbation
// ~1e-4 << fp16-pack absmax 0.0156).
// Returns bad=true for cond_F(J) > 2e3 (caller redoes in fp64).
__device__ __forceinline__ bool polar_f32(const float J[9], float X[9])
{
#pragma unroll
    for (int t = 0; t < 9; ++t) X[t] = J[t];
    bool bad = false;
#pragma unroll
    for (int it = 0; it < 5; ++it) {
        float C[9];
        C[0] = X[4] * X[8] - X[5] * X[7];
        C[1] = X[5] * X[6] - X[3] * X[8];
        C[2] = X[3] * X[7] - X[4] * X[6];
        C[3] = X[2] * X[7] - X[1] * X[8];
        C[4] = X[0] * X[8] - X[2] * X[6];
        C[5] = X[1] * X[6] - X[0] * X[7];
        C[6] = X[1] * X[5] - X[2] * X[4];
        C[7] = X[2] * X[3] - X[0] * X[5];
        C[8] = X[0] * X[4] - X[1] * X[3];
        const float det = X[0] * C[0] + X[1] * C[1] + X[2] * C[2];
        float a, b;
        if (it < 3) {
            float nX = 0.0f, nC = 0.0f;
#pragma unroll
            for (int t = 0; t < 9; ++t) { nX += X[t] * X[t]; nC += C[t] * C[t]; }
            if (it == 0)
                bad = !(nX * nC < 4.0e6f * det * det);  // condF > 2e3 (sqrt-free)
            const float s = __builtin_amdgcn_sqrtf(nC * __builtin_amdgcn_rcpf(nX));
            const float r = __builtin_amdgcn_rsqf(s * fabsf(det));
            a = 0.5f * s * r;
            b = copysignf(0.5f * r, det);
        } else {
            a = 0.5f;
            b = 0.5f * __builtin_amdgcn_rcpf(det);
        }
#pragma unroll
        for (int t = 0; t < 9; ++t) X[t] = a * X[t] + b * C[t];
    }
    return bad;
}

// ---- fp64 fallback (rare; inline & unrolled => register-resident) -----------
__device__ __forceinline__ void polar_f64(const float J[9], float X[9])
{
    double Y[9];
#pragma unroll
    for (int t = 0; t < 9; ++t) Y[t] = (double)J[t];
    for (int it = 0; it < 20; ++it) {
        double C[9];
        C[0] = Y[4] * Y[8] - Y[5] * Y[7];
        C[1] = Y[5] * Y[6] - Y[3] * Y[8];
        C[2] = Y[3] * Y[7] - Y[4] * Y[6];
        C[3] = Y[2] * Y[7] - Y[1] * Y[8];
        C[4] = Y[0] * Y[8] - Y[2] * Y[6];
        C[5] = Y[1] * Y[6] - Y[0] * Y[7];
        C[6] = Y[1] * Y[5] - Y[2] * Y[4];
        C[7] = Y[2] * Y[3] - Y[0] * Y[5];
        C[8] = Y[0] * Y[4] - Y[1] * Y[3];
        const double det = Y[0] * C[0] + Y[1] * C[1] + Y[2] * C[2];
        if (!(fabs(det) > 1e-300)) break;
        double nX = 0.0, nC = 0.0;
#pragma unroll
        for (int t = 0; t < 9; ++t) { nX += Y[t] * Y[t]; nC += C[t] * C[t]; }
        const double g = sqrt(sqrt(nC) / (fabs(det) * sqrt(nX)));
        const double a = 0.5 * g;
        const double b = 0.5 / (g * det);
        double diff2 = 0.0, n2 = 0.0;
#pragma unroll
        for (int t = 0; t < 9; ++t) {
            const double y = a * Y[t] + b * C[t];
            const double d = y - Y[t];
            diff2 += d * d; n2 += y * y;
            Y[t] = y;
        }
        if (diff2 <= 1e-26 * n2) break;
    }
#pragma unroll
    for (int t = 0; t < 9; ++t) X[t] = (float)Y[t];
}

// ---------------- Pass B: warp + polar + congruence --------------------------
// R10 = R2 structure (best measured: 65 µs) with a surgical line-request cut.
// Counters model: ~560 L2 line-requests/wave (gathers ~450, ddf ~84,
// stores 24) = 117 req/cy chip-wide ≈ 92% of the 128/cy L2-channel rate —
// the binding resource (ILP/scheduling R6-R8 neutral; LDS restructure R9
// regressed on its own overheads). This round removes the k+-1 ddf neighbor
// loads: lanes are z-consecutive, so p[id+-1] is a 1-lane shuffle; only the
// wave-edge lanes (0,63) need a predicated 1-lane load, and grid borders
// clamp to u (np.gradient one-sided). 21 -> 15 full loads/thread.
__global__ __launch_bounds__(256) void warp_dti_kernel(
    const vuint3* __restrict__ aos,
    const float* __restrict__ ddf,
    float* __restrict__ out)
{
    const int bid = blockIdx.x;                     // 8192 blocks
    const int sb = ((bid & 7) << 10) | (bid >> 3);  // XCD i-slab swizzle
    const int id = sb * 256 + (int)threadIdx.x;
    const int lane = (int)threadIdx.x & 63;
    const int k = id & (DIM - 1);
    const int j = (id >> 7) & (DIM - 1);
    const int i = id >> 14;

    const float* __restrict__ p0_ = ddf;
    const float* __restrict__ p1_ = ddf + NVOX;
    const float* __restrict__ p2_ = ddf + 2 * NVOX;

    // ---- Jacobian: J = I + grad(ddf) (np.gradient semantics) ----
    const int im = (i > 0) ? i - 1 : 0, ip = (i < DIM - 1) ? i + 1 : DIM - 1;
    const int jm = (j > 0) ? j - 1 : 0, jp = (j < DIM - 1) ? j + 1 : DIM - 1;
    const float si = (ip - im == 2) ? 0.5f : 1.0f;
    const float sj = (jp - jm == 2) ? 0.5f : 1.0f;
    const float sk = (k > 0 && k < DIM - 1) ? 0.5f : 1.0f;

    const int l_ip = (ip << 14) | (j << 7) | k;
    const int l_im = (im << 14) | (j << 7) | k;
    const int l_jp = (i << 14) | (jp << 7) | k;
    const int l_jm = (i << 14) | (jm << 7) | k;

    float J[9];
    float u[3];
#pragma unroll
    for (int c = 0; c < 3; ++c) {
        const float* __restrict__ p = (c == 0) ? p0_ : (c == 1) ? p1_ : p2_;
        u[c] = p[id];
        // k-neighbors from the wave (lanes are z-consecutive):
        float kp_raw = __shfl_down(u[c], 1, 64);   // value at id+1 for lane<63
        float km_raw = __shfl_up(u[c], 1, 64);     // value at id-1 for lane>0
        if (lane == 63 && k < DIM - 1) kp_raw = p[id + 1];  // 1-lane load
        if (lane == 0 && k > 0)        km_raw = p[id - 1];  // 1-lane load
        const float kpv = (k < DIM - 1) ? kp_raw : u[c];    // border clamp
        const float kmv = (k > 0)       ? km_raw : u[c];
        J[c * 3 + 0] = (p[l_ip] - p[l_im]) * si;
        J[c * 3 + 1] = (p[l_jp] - p[l_jm]) * sj;
        J[c * 3 + 2] = (kpv - kmv) * sk;
        J[c * 3 + c] += 1.0f;
    }

    // ---- Trilinear warp from fp16 AoS (border padding) ----
    const float cx = fminf(fmaxf((float)i + u[0], 0.0f), (float)(DIM - 1));
    const float cy = fminf(fmaxf((float)j + u[1], 0.0f), (float)(DIM - 1));
    const float cz = fminf(fmaxf((float)k + u[2], 0.0f), (float)(DIM - 1));
    const float x0f = floorf(cx), y0f = floorf(cy), z0f = floorf(cz);
    const float fx = cx - x0f, fy = cy - y0f, fz = cz - z0f;
    const int x0 = (int)x0f, y0 = (int)y0f, z0 = (int)z0f;
    const int x1 = min(x0 + 1, DIM - 1);
    const int y1 = min(y0 + 1, DIM - 1);
    const int z1 = min(z0 + 1, DIM - 1);

    const float gx0 = 1.0f - fx, gy0 = 1.0f - fy, gz0 = 1.0f - fz;

    // delta addressing: corners = base + {0,dz} + {0,dy} + {0,dx}
    const int dz = z1 - z0;
    const int dy = (y1 - y0) << 7;
    const int dx = (x1 - x0) << 14;
    const int b000 = (x0 << 14) | (y0 << 7) | z0;

    float acc0 = 0.0f, acc1 = 0.0f, acc2 = 0.0f;
    float acc3 = 0.0f, acc4 = 0.0f, acc5 = 0.0f;

    // fmaf((float)half, wt, acc) folds to v_fma_mix_f32 (f32 accumulate,
    // no separate v_cvt). z-pair corners issued back-to-back so their
    // (usually shared) cache line merges in the MSHR.
    auto gat = [&](int lin, float wt) {
        const vuint3 q = aos[lin];
        const unsigned int qx = q.x, qy = q.y, qz = q.z;
        const __half2 h01 = *reinterpret_cast<const __half2*>(&qx);
        const __half2 h23 = *reinterpret_cast<const __half2*>(&qy);
        const __half2 h45 = *reinterpret_cast<const __half2*>(&qz);
        acc0 = fmaf(__half2float(__low2half(h01)), wt, acc0);
        acc1 = fmaf(__half2float(__high2half(h01)), wt, acc1);
        acc2 = fmaf(__half2float(__low2half(h23)), wt, acc2);
        acc3 = fmaf(__half2float(__high2half(h23)), wt, acc3);
        acc4 = fmaf(__half2float(__low2half(h45)), wt, acc4);
        acc5 = fmaf(__half2float(__high2half(h45)), wt, acc5);
    };

    gat(b000,                gx0 * gy0 * gz0);
    gat(b000 + dz,           gx0 * gy0 * fz);
    gat(b000 + dy,           gx0 * fy * gz0);
    gat(b000 + dy + dz,      gx0 * fy * fz);
    gat(b000 + dx,           fx * gy0 * gz0);
    gat(b000 + dx + dz,      fx * gy0 * fz);
    gat(b000 + dx + dy,      fx * fy * gz0);
    gat(b000 + dx + dy + dz, fx * fy * fz);

    // ---- Polar factor ----
    float X[9];
    const bool bad = polar_f32(J, X);
    if (__builtin_expect(bad, 0)) polar_f64(J, X);

    // ---- Dp = R^T M R ----
    const float M00 = acc0, M01 = acc1, M11 = acc2;
    const float M02 = acc3, M12 = acc4, M22 = acc5;
    float P[9];  // P = M * R
    P[0] = M00 * X[0] + M01 * X[3] + M02 * X[6];
    P[1] = M00 * X[1] + M01 * X[4] + M02 * X[7];
    P[2] = M00 * X[2] + M01 * X[5] + M02 * X[8];
    P[3] = M01 * X[0] + M11 * X[3] + M12 * X[6];
    P[4] = M01 * X[1] + M11 * X[4] + M12 * X[7];
    P[5] = M01 * X[2] + M11 * X[5] + M12 * X[8];
    P[6] = M02 * X[0] + M12 * X[3] + M22 * X[6];
    P[7] = M02 * X[1] + M12 * X[4] + M22 * X[7];
    P[8] = M02 * X[2] + M12 * X[5] + M22 * X[8];

    // Output: 48 MB, zero reuse -> non-temporal so it doesn't evict aos
    // from L2/L3 between gathers.
    __builtin_nontemporal_store(X[0] * P[0] + X[3] * P[3] + X[6] * P[6], &out[0 * NVOX + id]);
    __builtin_nontemporal_store(X[1] * P[0] + X[4] * P[3] + X[7] * P[6], &out[1 * NVOX + id]);
    __builtin_nontemporal_store(X[1] * P[1] + X[4] * P[4] + X[7] * P[7], &out[2 * NVOX + id]);
    __builtin_nontemporal_store(X[2] * P[0] + X[5] * P[3] + X[8] * P[6], &out[3 * NVOX + id]);
    __builtin_nontemporal_store(X[2] * P[1] + X[5] * P[4] + X[8] * P[7], &out[4 * NVOX + id]);
    __builtin_nontemporal_store(X[2] * P[2] + X[5] * P[5] + X[8] * P[8], &out[5 * NVOX + id]);
}

extern "C" void kernel_launch(void* const* d_in, const int* in_sizes, int n_in,
                              void* d_out, int out_size, void* d_ws, size_t ws_size,
                              hipStream_t stream) {
    const float* dti = (const float*)d_in[0];
    const float* ddf = (const float*)d_in[1];
    float* out = (float*)d_out;
    unsigned int* aos = (unsigned int*)d_ws;  // 2M voxels * 16 B = 32 MB scratch

    hipLaunchKernelGGL(pack_dti_kernel, dim3(NVOX / 1024), dim3(256), 0, stream,
                       dti, aos);
    hipLaunchKernelGGL(warp_dti_kernel, dim3(NVOX / 256), dim3(256), 0, stream,
                       (const vuint3*)aos, ddf, out);
}

// Round 8
// 168.720 us; speedup vs baseline: 1.1712x; 1.0169x over previous
//
#include <hip/hip_runtime.h>
#include <hip/hip_fp16.h>
#include <math.h>

#define DIM 128
#define NVOX (DIM*DIM*DIM)

// clang native vector types (HIP's float4/uint4 are classes — rejected by
// __builtin_nontemporal_load/store)
typedef float vfloat4 __attribute__((ext_vector_type(4)));
typedef unsigned int vuint4 __attribute__((ext_vector_type(4)));
typedef unsigned int vuint3 __attribute__((ext_vector_type(3)));  // sizeof==16
static_assert(sizeof(vuint3) == 16, "vuint3 must stride 16B over the AoS array");

// ---------------- Pass A: dti (6,NVOX) f32 SoA -> AoS fp16 16B/voxel ---------
// FULL 16B stores (R7 lesson: 12B stores leave 4B holes per 16B chunk ->
// partial-line RMW at L2/HBM cost ~3µs, more than the 8MB they saved).
// nt loads: dti is dead after this pass; keep it out of L2/L3 so the aos
// array stays resident for pass B's gathers. Same XCD swizzle as pass B.
__global__ __launch_bounds__(256) void pack_dti_kernel(
    const float* __restrict__ dti, vuint4* __restrict__ aos)
{
    const int bid = blockIdx.x;                    // 2048 blocks
    const int sb = ((bid & 7) << 8) | (bid >> 3);  // XCD i-slab swizzle
    const int id4 = (sb * 256 + (int)threadIdx.x) * 4;

    const vfloat4 v0 = __builtin_nontemporal_load(reinterpret_cast<const vfloat4*>(dti + 0 * NVOX + id4));
    const vfloat4 v1 = __builtin_nontemporal_load(reinterpret_cast<const vfloat4*>(dti + 1 * NVOX + id4));
    const vfloat4 v2 = __builtin_nontemporal_load(reinterpret_cast<const vfloat4*>(dti + 2 * NVOX + id4));
    const vfloat4 v3 = __builtin_nontemporal_load(reinterpret_cast<const vfloat4*>(dti + 3 * NVOX + id4));
    const vfloat4 v4 = __builtin_nontemporal_load(reinterpret_cast<const vfloat4*>(dti + 4 * NVOX + id4));
    const vfloat4 v5 = __builtin_nontemporal_load(reinterpret_cast<const vfloat4*>(dti + 5 * NVOX + id4));

    auto packone = [&](float a0, float a1, float a2, float a3, float a4,
                       float a5, int idx) {
        const __half2 h01 = __floats2half2_rn(a0, a1);
        const __half2 h23 = __floats2half2_rn(a2, a3);
        const __half2 h45 = __floats2half2_rn(a4, a5);
        vuint4 q;
        q.x = *reinterpret_cast<const unsigned int*>(&h01);
        q.y = *reinterpret_cast<const unsigned int*>(&h23);
        q.z = *reinterpret_cast<const unsigned int*>(&h45);
        q.w = 0u;
        aos[idx] = q;  // normal store: we WANT these lines in L2 for pass B
    };
    packone(v0.x, v1.x, v2.x, v3.x, v4.x, v5.x, id4 + 0);
    packone(v0.y, v1.y, v2.y, v3.y, v4.y, v5.y, id4 + 1);
    packone(v0.z, v1.z, v2.z, v3.z, v4.z, v5.z, id4 + 2);
    packone(v0.w, v1.w, v2.w, v3.w, v4.w, v5.w, id4 + 3);
}

// ---- fp32 polar factor: branch-free 3 scaled + 2 unscaled Newton ------------
// Fixed point: R = U @ Vh (SVD polar factor), sign(det) preserved.
// For cond<=2e3: scaled iters contract sigma-range 22 -> 2.5 -> 1.1, then
// unscaled e^2/2: 0.1 -> 5e-3 -> 1.3e-5 (orthogonality; output perturbation
// ~1e-4 << fp16-pack absmax 0.0156).
// Returns bad=true for cond_F(J) > 2e3 (caller redoes in fp64).
__device__ __forceinline__ bool polar_f32(const float J[9], float X[9])
{
#pragma unroll
    for (int t = 0; t < 9; ++t) X[t] = J[t];
    bool bad = false;
#pragma unroll
    for (int it = 0; it < 5; ++it) {
        float C[9];
        C[0] = X[4] * X[8] - X[5] * X[7];
        C[1] = X[5] * X[6] - X[3] * X[8];
        C[2] = X[3] * X[7] - X[4] * X[6];
        C[3] = X[2] * X[7] - X[1] * X[8];
        C[4] = X[0] * X[8] - X[2] * X[6];
        C[5] = X[1] * X[6] - X[0] * X[7];
        C[6] = X[1] * X[5] - X[2] * X[4];
        C[7] = X[2] * X[3] - X[0] * X[5];
        C[8] = X[0] * X[4] - X[1] * X[3];
        const float det = X[0] * C[0] + X[1] * C[1] + X[2] * C[2];
        float a, b;
        if (it < 3) {
            float nX = 0.0f, nC = 0.0f;
#pragma unroll
            for (int t = 0; t < 9; ++t) { nX += X[t] * X[t]; nC += C[t] * C[t]; }
            if (it == 0)
                bad = !(nX * nC < 4.0e6f * det * det);  // condF > 2e3 (sqrt-free)
            const float s = __builtin_amdgcn_sqrtf(nC * __builtin_amdgcn_rcpf(nX));
            const float r = __builtin_amdgcn_rsqf(s * fabsf(det));
            a = 0.5f * s * r;
            b = copysignf(0.5f * r, det);
        } else {
            a = 0.5f;
            b = 0.5f * __builtin_amdgcn_rcpf(det);
        }
#pragma unroll
        for (int t = 0; t < 9; ++t) X[t] = a * X[t] + b * C[t];
    }
    return bad;
}

// ---- fp64 fallback (rare; inline & unrolled => register-resident) -----------
__device__ __forceinline__ void polar_f64(const float J[9], float X[9])
{
    double Y[9];
#pragma unroll
    for (int t = 0; t < 9; ++t) Y[t] = (double)J[t];
    for (int it = 0; it < 20; ++it) {
        double C[9];
        C[0] = Y[4] * Y[8] - Y[5] * Y[7];
        C[1] = Y[5] * Y[6] - Y[3] * Y[8];
        C[2] = Y[3] * Y[7] - Y[4] * Y[6];
        C[3] = Y[2] * Y[7] - Y[1] * Y[8];
        C[4] = Y[0] * Y[8] - Y[2] * Y[6];
        C[5] = Y[1] * Y[6] - Y[0] * Y[7];
        C[6] = Y[1] * Y[5] - Y[2] * Y[4];
        C[7] = Y[2] * Y[3] - Y[0] * Y[5];
        C[8] = Y[0] * Y[4] - Y[1] * Y[3];
        const double det = Y[0] * C[0] + Y[1] * C[1] + Y[2] * C[2];
        if (!(fabs(det) > 1e-300)) break;
        double nX = 0.0, nC = 0.0;
#pragma unroll
        for (int t = 0; t < 9; ++t) { nX += Y[t] * Y[t]; nC += C[t] * C[t]; }
        const double g = sqrt(sqrt(nC) / (fabs(det) * sqrt(nX)));
        const double a = 0.5 * g;
        const double b = 0.5 / (g * det);
        double diff2 = 0.0, n2 = 0.0;
#pragma unroll
        for (int t = 0; t < 9; ++t) {
            const double y = a * Y[t] + b * C[t];
            const double d = y - Y[t];
            diff2 += d * d; n2 += y * y;
            Y[t] = y;
        }
        if (diff2 <= 1e-26 * n2) break;
    }
#pragma unroll
    for (int t = 0; t < 9; ++t) X[t] = (float)Y[t];
}

// ---------------- Pass B: warp + polar + congruence --------------------------
// Final config: R2 structure + shuffle k-neighbors (R7: measured neutral on
// time, strictly fewer loads). Seven structural variants (reorder, sched
// pinning, 2-voxel ILP, LDS staging, request cuts) pin this dispatch at
// 64.5-66.8 µs: the binding resource is the divergent-gather transaction
// service rate (16.8M random 12-16B reads; L1 can't hold the 4MB/XCD slab),
// not HBM (16%), not VALU issue (~12µs), not occupancy, not latency.
__global__ __launch_bounds__(256) void warp_dti_kernel(
    const vuint3* __restrict__ aos,
    const float* __restrict__ ddf,
    float* __restrict__ out)
{
    const int bid = blockIdx.x;                     // 8192 blocks
    const int sb = ((bid & 7) << 10) | (bid >> 3);  // XCD i-slab swizzle
    const int id = sb * 256 + (int)threadIdx.x;
    const int lane = (int)threadIdx.x & 63;
    const int k = id & (DIM - 1);
    const int j = (id >> 7) & (DIM - 1);
    const int i = id >> 14;

    const float* __restrict__ p0_ = ddf;
    const float* __restrict__ p1_ = ddf + NVOX;
    const float* __restrict__ p2_ = ddf + 2 * NVOX;

    // ---- Jacobian: J = I + grad(ddf) (np.gradient semantics) ----
    const int im = (i > 0) ? i - 1 : 0, ip = (i < DIM - 1) ? i + 1 : DIM - 1;
    const int jm = (j > 0) ? j - 1 : 0, jp = (j < DIM - 1) ? j + 1 : DIM - 1;
    const float si = (ip - im == 2) ? 0.5f : 1.0f;
    const float sj = (jp - jm == 2) ? 0.5f : 1.0f;
    const float sk = (k > 0 && k < DIM - 1) ? 0.5f : 1.0f;

    const int l_ip = (ip << 14) | (j << 7) | k;
    const int l_im = (im << 14) | (j << 7) | k;
    const int l_jp = (i << 14) | (jp << 7) | k;
    const int l_jm = (i << 14) | (jm << 7) | k;

    float J[9];
    float u[3];
#pragma unroll
    for (int c = 0; c < 3; ++c) {
        const float* __restrict__ p = (c == 0) ? p0_ : (c == 1) ? p1_ : p2_;
        u[c] = p[id];
        // k-neighbors from the wave (lanes are z-consecutive):
        float kp_raw = __shfl_down(u[c], 1, 64);   // value at id+1 for lane<63
        float km_raw = __shfl_up(u[c], 1, 64);     // value at id-1 for lane>0
        if (lane == 63 && k < DIM - 1) kp_raw = p[id + 1];  // 1-lane load
        if (lane == 0 && k > 0)        km_raw = p[id - 1];  // 1-lane load
        const float kpv = (k < DIM - 1) ? kp_raw : u[c];    // border clamp
        const float kmv = (k > 0)       ? km_raw : u[c];
        J[c * 3 + 0] = (p[l_ip] - p[l_im]) * si;
        J[c * 3 + 1] = (p[l_jp] - p[l_jm]) * sj;
        J[c * 3 + 2] = (kpv - kmv) * sk;
        J[c * 3 + c] += 1.0f;
    }

    // ---- Trilinear warp from fp16 AoS (border padding) ----
    const float cx = fminf(fmaxf((float)i + u[0], 0.0f), (float)(DIM - 1));
    const float cy = fminf(fmaxf((float)j + u[1], 0.0f), (float)(DIM - 1));
    const float cz = fminf(fmaxf((float)k + u[2], 0.0f), (float)(DIM - 1));
    const float x0f = floorf(cx), y0f = floorf(cy), z0f = floorf(cz);
    const float fx = cx - x0f, fy = cy - y0f, fz = cz - z0f;
    const int x0 = (int)x0f, y0 = (int)y0f, z0 = (int)z0f;
    const int x1 = min(x0 + 1, DIM - 1);
    const int y1 = min(y0 + 1, DIM - 1);
    const int z1 = min(z0 + 1, DIM - 1);

    const float gx0 = 1.0f - fx, gy0 = 1.0f - fy, gz0 = 1.0f - fz;

    // delta addressing: corners = base + {0,dz} + {0,dy} + {0,dx}
    const int dz = z1 - z0;
    const int dy = (y1 - y0) << 7;
    const int dx = (x1 - x0) << 14;
    const int b000 = (x0 << 14) | (y0 << 7) | z0;

    float acc0 = 0.0f, acc1 = 0.0f, acc2 = 0.0f;
    float acc3 = 0.0f, acc4 = 0.0f, acc5 = 0.0f;

    // fmaf((float)half, wt, acc) folds to v_fma_mix_f32 (f32 accumulate,
    // no separate v_cvt). z-pair corners issued back-to-back so their
    // (usually shared) cache line merges in the MSHR.
    auto gat = [&](int lin, float wt) {
        const vuint3 q = aos[lin];
        const unsigned int qx = q.x, qy = q.y, qz = q.z;
        const __half2 h01 = *reinterpret_cast<const __half2*>(&qx);
        const __half2 h23 = *reinterpret_cast<const __half2*>(&qy);
        const __half2 h45 = *reinterpret_cast<const __half2*>(&qz);
        acc0 = fmaf(__half2float(__low2half(h01)), wt, acc0);
        acc1 = fmaf(__half2float(__high2half(h01)), wt, acc1);
        acc2 = fmaf(__half2float(__low2half(h23)), wt, acc2);
        acc3 = fmaf(__half2float(__high2half(h23)), wt, acc3);
        acc4 = fmaf(__half2float(__low2half(h45)), wt, acc4);
        acc5 = fmaf(__half2float(__high2half(h45)), wt, acc5);
    };

    gat(b000,                gx0 * gy0 * gz0);
    gat(b000 + dz,           gx0 * gy0 * fz);
    gat(b000 + dy,           gx0 * fy * gz0);
    gat(b000 + dy + dz,      gx0 * fy * fz);
    gat(b000 + dx,           fx * gy0 * gz0);
    gat(b000 + dx + dz,      fx * gy0 * fz);
    gat(b000 + dx + dy,      fx * fy * gz0);
    gat(b000 + dx + dy + dz, fx * fy * fz);

    // ---- Polar factor ----
    float X[9];
    const bool bad = polar_f32(J, X);
    if (__builtin_expect(bad, 0)) polar_f64(J, X);

    // ---- Dp = R^T M R ----
    const float M00 = acc0, M01 = acc1, M11 = acc2;
    const float M02 = acc3, M12 = acc4, M22 = acc5;
    float P[9];  // P = M * R
    P[0] = M00 * X[0] + M01 * X[3] + M02 * X[6];
    P[1] = M00 * X[1] + M01 * X[4] + M02 * X[7];
    P[2] = M00 * X[2] + M01 * X[5] + M02 * X[8];
    P[3] = M01 * X[0] + M11 * X[3] + M12 * X[6];
    P[4] = M01 * X[1] + M11 * X[4] + M12 * X[7];
    P[5] = M01 * X[2] + M11 * X[5] + M12 * X[8];
    P[6] = M02 * X[0] + M12 * X[3] + M22 * X[6];
    P[7] = M02 * X[1] + M12 * X[4] + M22 * X[7];
    P[8] = M02 * X[2] + M12 * X[5] + M22 * X[8];

    // Output: 48 MB, zero reuse -> non-temporal so it doesn't evict aos
    // from L2/L3 between gathers.
    __builtin_nontemporal_store(X[0] * P[0] + X[3] * P[3] + X[6] * P[6], &out[0 * NVOX + id]);
    __builtin_nontemporal_store(X[1] * P[0] + X[4] * P[3] + X[7] * P[6], &out[1 * NVOX + id]);
    __builtin_nontemporal_store(X[1] * P[1] + X[4] * P[4] + X[7] * P[7], &out[2 * NVOX + id]);
    __builtin_nontemporal_store(X[2] * P[0] + X[5] * P[3] + X[8] * P[6], &out[3 * NVOX + id]);
    __builtin_nontemporal_store(X[2] * P[1] + X[5] * P[4] + X[8] * P[7], &out[4 * NVOX + id]);
    __builtin_nontemporal_store(X[2] * P[2] + X[5] * P[5] + X[8] * P[8], &out[5 * NVOX + id]);
}

extern "C" void kernel_launch(void* const* d_in, const int* in_sizes, int n_in,
                              void* d_out, int out_size, void* d_ws, size_t ws_size,
                              hipStream_t stream) {
    const float* dti = (const float*)d_in[0];
    const float* ddf = (const float*)d_in[1];
    float* out = (float*)d_out;
    vuint4* aos = (vuint4*)d_ws;  // 2M voxels * 16 B = 32 MB scratch

    hipLaunchKernelGGL(pack_dti_kernel, dim3(NVOX / 1024), dim3(256), 0, stream,
                       dti, aos);
    hipLaunchKernelGGL(warp_dti_kernel, dim3(NVOX / 256), dim3(256), 0, stream,
                       (const vuint3*)aos, ddf, out);
}